// Round 14
// baseline (401.949 us; speedup 1.0000x reference)
//
#include <hip/hip_runtime.h>

#define C 16
#define TAPS 27
#define NCONV 17
#define LISTCAP 98304
#define NPAIR 14

typedef _Float16 half8 __attribute__((ext_vector_type(8)));
typedef _Float16 half4 __attribute__((ext_vector_type(4)));
typedef float f32x4 __attribute__((ext_vector_type(4)));

// ---- prep: x NCDHW->NDHWC fp16, zero P1h, per-block active counts, weight prep ----
// Wh[l][pair][lane][8]: lane co=lane&15, g=lane>>4; k=8g+j; ci=k&15; tap=2p+(k>>4).
__global__ void prep_kernel(const float* __restrict__ x, const int* __restrict__ mask_idx,
                            _Float16* __restrict__ P0h, _Float16* __restrict__ P1h,
                            const float* __restrict__ W, _Float16* __restrict__ Wh,
                            int* __restrict__ counts) {
    const int n96 = 96 * 96 * 96;
    int b = blockIdx.x;
    if (b < 3456) {
        int v = b * 256 + threadIdx.x;  // n96 == 3456*256 exactly
        half8 h0, h1;
#pragma unroll
        for (int c = 0; c < 8; c++) h0[c] = (_Float16)x[(long)c * n96 + v];
#pragma unroll
        for (int c = 0; c < 8; c++) h1[c] = (_Float16)x[(long)(c + 8) * n96 + v];
        half8* dp = reinterpret_cast<half8*>(P0h + (long)v * C);
        dp[0] = h0;
        dp[1] = h1;
        half8 zz = {};
        half8* zp = reinterpret_cast<half8*>(P1h + (long)v * C);
        zp[0] = zz;
        zp[1] = zz;
        int act = (mask_idx[v] == 0);
        unsigned long long bl = __ballot(act);
        __shared__ int wsum[4];
        int wid = threadIdx.x >> 6, lane = threadIdx.x & 63;
        if (lane == 0) wsum[wid] = __popcll(bl);
        __syncthreads();
        if (threadIdx.x == 0) counts[b] = wsum[0] + wsum[1] + wsum[2] + wsum[3];
    } else {
        int i = (b - 3456) * 256 + threadIdx.x;
        const int total = NCONV * NPAIR * 64 * 8;
        if (i < total) {
            int j = i & 7;
            int lane = (i >> 3) & 63;
            int p = (i >> 9) % NPAIR;
            int l = (i >> 9) / NPAIR;
            int co = lane & 15;
            int g = lane >> 4;
            int k = 8 * g + j;
            int ci = k & 15;
            int tap = 2 * p + (k >> 4);
            float val = (tap < TAPS) ? W[((l * C + co) * C + ci) * TAPS + tap] : 0.f;
            Wh[i] = (_Float16)val;
        }
    }
}

__global__ void scan_kernel(const int* __restrict__ counts, int* __restrict__ offsets,
                            int* __restrict__ nact, int nb) {
    __shared__ int s[256];
    int t = threadIdx.x;
    const int CH = (nb + 255) / 256;
    int base = t * CH, sum = 0;
    for (int j = 0; j < CH; j++)
        if (base + j < nb) sum += counts[base + j];
    s[t] = sum;
    __syncthreads();
    for (int off = 1; off < 256; off <<= 1) {
        int v = (t >= off) ? s[t - off] : 0;
        __syncthreads();
        s[t] += v;
        __syncthreads();
    }
    int run = s[t] - sum;
    for (int j = 0; j < CH; j++) {
        if (base + j < nb) {
            offsets[base + j] = run;
            run += counts[base + j];
        }
    }
    if (t == 255) *nact = s[255];
}

__global__ void scatter_kernel(const int* __restrict__ mi, const int* __restrict__ offsets,
                               int* __restrict__ list, int n, int cap) {
    int i = blockIdx.x * 256 + threadIdx.x;
    int act = (i < n) && (mi[i] == 0);
    unsigned long long b = __ballot(act);
    __shared__ int wsum[4];
    int wid = threadIdx.x >> 6, lane = threadIdx.x & 63;
    if (lane == 0) wsum[wid] = __popcll(b);
    __syncthreads();
    int wbase = 0;
    for (int w = 0; w < wid; w++) wbase += wsum[w];
    int prefix = __popcll(b & ((1ull << lane) - 1));
    if (act) {
        int pos = offsets[blockIdx.x] + wbase + prefix;
        if (pos < cap) list[pos] = i;
    }
}

// ---- all mask pools directly from mask_idx (composed windows, gap-free) ----
__global__ void allpools_kernel(const int* __restrict__ mi, float* __restrict__ m48,
                                float* __restrict__ m24, float* __restrict__ m12,
                                float* __restrict__ m6) {
    int b = blockIdx.x;
    int tid = threadIdx.x;
    auto rd = [&](int zz, int yy, int xx) -> float {
        if ((unsigned)zz >= 96u || (unsigned)yy >= 96u || (unsigned)xx >= 96u) return 0.f;
        return (mi[((long)zz * 96 + yy) * 96 + xx] == 0) ? 1.f : 0.f;
    };
    if (b < 432) {  // m48: thread per voxel, window [2c-1, 2c+1]
        int i = b * 256 + tid;
        int x = i % 48, y = (i / 48) % 48, z = i / (48 * 48);
        float m = 0.f;
        for (int dz = 0; dz < 3; dz++)
            for (int dy = 0; dy < 3; dy++)
                for (int dx = 0; dx < 3; dx++)
                    m = fmaxf(m, rd(2 * z - 1 + dz, 2 * y - 1 + dy, 2 * x - 1 + dx));
        m48[i] = m;
    } else if (b < 486) {  // m24: thread per voxel, window [4c-3, 4c+3]
        int i = (b - 432) * 256 + tid;
        int x = i % 24, y = (i / 24) % 24, z = i / (24 * 24);
        float m = 0.f;
        for (int dz = 0; dz < 7; dz++)
            for (int dy = 0; dy < 7; dy++)
                for (int dx = 0; dx < 7; dx++)
                    m = fmaxf(m, rd(4 * z - 3 + dz, 4 * y - 3 + dy, 4 * x - 3 + dx));
        m24[i] = m;
    } else if (b < 918) {  // m12: wave per voxel, window 15^3 = [8c-7, 8c+7]
        int wv = (b - 486) * 4 + (tid >> 6);
        int lane = tid & 63;
        int x = wv % 12, y = (wv / 12) % 12, z = wv / (12 * 12);
        float m = 0.f;
        for (int k = lane; k < 3375; k += 64) {
            int dz = k / 225, r = k % 225, dy = r / 15, dx = r % 15;
            m = fmaxf(m, rd(8 * z - 7 + dz, 8 * y - 7 + dy, 8 * x - 7 + dx));
        }
        for (int off = 32; off; off >>= 1) m = fmaxf(m, __shfl_xor(m, off));
        if (lane == 0) m12[wv] = m;
    } else {  // m6: wave per voxel, window 31^3 = [16c-15, 16c+15]
        int wv = (b - 918) * 4 + (tid >> 6);
        int lane = tid & 63;
        int x = wv % 6, y = (wv / 6) % 6, z = wv / 36;
        float m = 0.f;
        for (int k = lane; k < 29791; k += 64) {
            int dz = k / 961, r = k % 961, dy = r / 31, dx = r % 31;
            m = fmaxf(m, rd(16 * z - 15 + dz, 16 * y - 15 + dy, 16 * x - 15 + dx));
        }
        for (int off = 32; off; off >>= 1) m = fmaxf(m, __shfl_xor(m, off));
        if (lane == 0) m6[wv] = m;
    }
}

// ---- MFMA conv (r13-proven) + optional fused fp32 NCDHW output ----
template <int STRIDE, bool SPARSE, bool WF32>
__global__ __launch_bounds__(256) void mconv_kernel(
    const _Float16* __restrict__ in, _Float16* __restrict__ out,
    const float* __restrict__ mask, const int* __restrict__ list,
    const int* __restrict__ nact, const _Float16* __restrict__ Whl,
    const float* __restrict__ bs, const float* __restrict__ bb,
    int Din, int Dout, float* __restrict__ outf) {
    int n = Dout * Dout * Dout;
    int nv;
    if (SPARSE) {
        nv = *nact;
        if (nv > LISTCAP) nv = LISTCAP;
    } else {
        nv = n;
    }
    int tile = blockIdx.x * 4 + (threadIdx.x >> 6);
    if (tile * 16 >= nv) return;  // per-wave exit (no barriers)

    int lane = threadIdx.x & 63;
    int col = lane & 15;
    int g = lane >> 4;
    int s = tile * 16 + col;
    bool val = s < nv;
    int v = 0;
    if (SPARSE) {
        if (val) v = list[s];
    } else {
        v = val ? s : 0;
    }
    int x = v % Dout, y = (v / Dout) % Dout, z = v / (Dout * Dout);

    const half8* wf = reinterpret_cast<const half8*>(Whl);
    half8 a[NPAIR];
#pragma unroll
    for (int p = 0; p < NPAIR; p++) a[p] = wf[p * 64 + lane];

    int half_off = (g & 1) * 8;
    int tg = g >> 1;

    f32x4 acc = {0.f, 0.f, 0.f, 0.f};
#pragma unroll
    for (int p = 0; p < NPAIR; p++) {
        int tap = 2 * p + tg;
        if (tap > TAPS - 1) tap = TAPS - 1;  // dummy half: weights are 0
        int kz = tap / 9, ky = (tap / 3) % 3, kx = tap % 3;
        int zz = STRIDE * z - 1 + kz;
        int yy = STRIDE * y - 1 + ky;
        int xx = STRIDE * x - 1 + kx;
        bool ok = val && ((unsigned)zz < (unsigned)Din) && ((unsigned)yy < (unsigned)Din) &&
                  ((unsigned)xx < (unsigned)Din);
        half8 b = {};
        if (ok) {
            b = *reinterpret_cast<const half8*>(
                in + (long)((zz * Din + yy) * Din + xx) * C + half_off);
        }
        acc = __builtin_amdgcn_mfma_f32_16x16x32_f16(a[p], b, acc, 0, 0, 0);
    }

    if (val) {
        float mk = SPARSE ? 1.f : mask[v];
        int cob = g * 4;
        half4 r;
#pragma unroll
        for (int j = 0; j < 4; j++) {
            float t = fmaxf(acc[j] * bs[cob + j] + bb[cob + j], 0.f) * mk;
            r[j] = (_Float16)t;
            if (WF32) outf[(long)(cob + j) * n + v] = t;
        }
        *reinterpret_cast<half4*>(out + (long)v * C + cob) = r;
    }
}

// ---- fused 12^3 + 6^3 levels: 8 conv layers in one block, acts in LDS ----
__global__ __launch_bounds__(512) void fused_tail(
    const _Float16* __restrict__ gin, const float* __restrict__ m12,
    const float* __restrict__ m6, const _Float16* __restrict__ Wh,
    const float* __restrict__ bs, const float* __restrict__ bb,
    float* __restrict__ out3, float* __restrict__ out4) {
    extern __shared__ _Float16 lds[];
    _Float16* H0 = lds;            // 1728*16
    _Float16* H1 = lds + 27648;    // 1728*16
    _Float16* G0 = lds + 55296;    // 216*16
    _Float16* G1 = lds + 58752;    // 216*16

    int tid = threadIdx.x;
    int lane = tid & 63;
    int wid = tid >> 6;  // 0..7
    int col = lane & 15, g = lane >> 4;
    int ho = (g & 1) * 8, tg = g >> 1;

    auto layer = [&](const _Float16* ginp, const _Float16* lin, _Float16* lout,
                     int Din, int Dout, int stride, int lidx,
                     const float* mk, float* outf) {
        int n = Dout * Dout * Dout;
        const half8* wf = reinterpret_cast<const half8*>(Wh + (long)lidx * NPAIR * 64 * 8);
        half8 a[NPAIR];
#pragma unroll
        for (int p = 0; p < NPAIR; p++) a[p] = wf[p * 64 + lane];
        const float* bsl = bs + lidx * C;
        const float* bbl = bb + lidx * C;
        int ntiles = (n + 15) / 16;
        for (int t = wid; t < ntiles; t += 8) {
            int s = t * 16 + col;
            bool val = s < n;
            int v = val ? s : 0;
            int x = v % Dout, y = (v / Dout) % Dout, z = v / (Dout * Dout);
            f32x4 acc = {0.f, 0.f, 0.f, 0.f};
#pragma unroll
            for (int p = 0; p < NPAIR; p++) {
                int tap = 2 * p + tg;
                if (tap > TAPS - 1) tap = TAPS - 1;
                int kz = tap / 9, ky = (tap / 3) % 3, kx = tap % 3;
                int zz = stride * z - 1 + kz;
                int yy = stride * y - 1 + ky;
                int xx = stride * x - 1 + kx;
                bool ok = val && ((unsigned)zz < (unsigned)Din) &&
                          ((unsigned)yy < (unsigned)Din) && ((unsigned)xx < (unsigned)Din);
                half8 b = {};
                if (ok) {
                    long off = (long)((zz * Din + yy) * Din + xx) * C + ho;
                    b = ginp ? *reinterpret_cast<const half8*>(ginp + off)
                             : *reinterpret_cast<const half8*>(lin + off);
                }
                acc = __builtin_amdgcn_mfma_f32_16x16x32_f16(a[p], b, acc, 0, 0, 0);
            }
            if (val) {
                float mkv = mk[v];
                int cob = g * 4;
                half4 r;
#pragma unroll
                for (int j = 0; j < 4; j++) {
                    float tt = fmaxf(acc[j] * bsl[cob + j] + bbl[cob + j], 0.f) * mkv;
                    r[j] = (_Float16)tt;
                    if (outf) outf[(long)(cob + j) * n + v] = tt;
                }
                *reinterpret_cast<half4*>(lout + (long)v * C + cob) = r;
            }
        }
        __syncthreads();
    };

    layer(gin, nullptr, H0, 24, 12, 2, 9, m12, nullptr);
    layer(nullptr, H0, H1, 12, 12, 1, 10, m12, nullptr);
    layer(nullptr, H1, H0, 12, 12, 1, 11, m12, nullptr);
    layer(nullptr, H0, H1, 12, 12, 1, 12, m12, out3);   // net3
    layer(nullptr, H1, G0, 12, 6, 2, 13, m6, nullptr);
    layer(nullptr, G0, G1, 6, 6, 1, 14, m6, nullptr);
    layer(nullptr, G1, G0, 6, 6, 1, 15, m6, nullptr);
    layer(nullptr, G0, G1, 6, 6, 1, 16, m6, out4);      // net4
}

extern "C" void kernel_launch(void* const* d_in, const int* in_sizes, int n_in,
                              void* d_out, int out_size, void* d_ws, size_t ws_size,
                              hipStream_t stream) {
    const float* x = (const float*)d_in[0];
    const int* mask_idx = (const int*)d_in[1];
    const float* W = (const float*)d_in[2];
    const float* bs = (const float*)d_in[3];
    const float* bb = (const float*)d_in[4];
    float* out = (float*)d_out;

    const int n96 = 96 * 96 * 96;
    const int n48 = 48 * 48 * 48;
    const int n24 = 24 * 24 * 24;
    const int n12 = 12 * 12 * 12;
    const int n6 = 6 * 6 * 6;
    const int NB = 3456;

    _Float16* P0h = (_Float16*)d_ws;
    _Float16* P1h = P0h + (long)C * n96;
    float* m48 = (float*)(P1h + (long)C * n96);
    float* m24 = m48 + n48;
    float* m12 = m24 + n24;
    float* m6 = m12 + n12;
    _Float16* Wh = (_Float16*)(m6 + n6);  // [17][14][64][8]
    int* list = (int*)(Wh + (long)NCONV * NPAIR * 64 * 8);
    int* counts = list + LISTCAP;
    int* offsets = counts + NB;
    int* nact = offsets + NB;

    const int LDSB = (2 * 1728 * 16 + 2 * 216 * 16) * (int)sizeof(_Float16);  // 124416
    hipFuncSetAttribute(reinterpret_cast<const void*>(&fused_tail),
                        hipFuncAttributeMaxDynamicSharedMemorySize, LDSB);

    // 1. prep (transpose + zero + counts + weights)
    hipLaunchKernelGGL(prep_kernel, dim3(3456 + 476), dim3(256), 0, stream,
                       x, mask_idx, P0h, P1h, W, Wh, counts);
    // 2-3. compaction
    hipLaunchKernelGGL(scan_kernel, dim3(1), dim3(256), 0, stream, counts, offsets, nact, NB);
    hipLaunchKernelGGL(scatter_kernel, dim3(NB), dim3(256), 0, stream, mask_idx, offsets, list,
                       n96, LISTCAP);
    // 4. all mask pools
    hipLaunchKernelGGL(allpools_kernel, dim3(972), dim3(256), 0, stream,
                       mask_idx, m48, m24, m12, m6);

    auto mblk = [&](long nvox) { return dim3((unsigned)((nvox + 63) / 64)); };
    auto WL = [&](int l) { return Wh + (long)l * NPAIR * 64 * 8; };

    // 5-6. sparse 96 level
    hipLaunchKernelGGL((mconv_kernel<1, true, false>), mblk(LISTCAP), dim3(256), 0, stream,
                       P0h, P1h, (const float*)nullptr, list, nact, WL(0), bs, bb, 96, 96,
                       (float*)nullptr);
    hipLaunchKernelGGL((mconv_kernel<1, true, false>), mblk(LISTCAP), dim3(256), 0, stream,
                       P1h, P0h, (const float*)nullptr, list, nact, WL(1), bs + C, bb + C, 96, 96,
                       (float*)nullptr);
    // 7-9. 48 level (dense); L4 dual-writes net1
    hipLaunchKernelGGL((mconv_kernel<2, false, false>), mblk(n48), dim3(256), 0, stream,
                       P0h, P1h, m48, list, nact, WL(2), bs + 2 * C, bb + 2 * C, 96, 48,
                       (float*)nullptr);
    hipLaunchKernelGGL((mconv_kernel<1, false, false>), mblk(n48), dim3(256), 0, stream,
                       P1h, P0h, m48, list, nact, WL(3), bs + 3 * C, bb + 3 * C, 48, 48,
                       (float*)nullptr);
    hipLaunchKernelGGL((mconv_kernel<1, false, true>), mblk(n48), dim3(256), 0, stream,
                       P0h, P1h, m48, list, nact, WL(4), bs + 4 * C, bb + 4 * C, 48, 48,
                       out);
    // 10-13. 24 level (dense); L8 dual-writes net2
    hipLaunchKernelGGL((mconv_kernel<2, false, false>), mblk(n24), dim3(256), 0, stream,
                       P1h, P0h, m24, list, nact, WL(5), bs + 5 * C, bb + 5 * C, 48, 24,
                       (float*)nullptr);
    hipLaunchKernelGGL((mconv_kernel<1, false, false>), mblk(n24), dim3(256), 0, stream,
                       P0h, P1h, m24, list, nact, WL(6), bs + 6 * C, bb + 6 * C, 24, 24,
                       (float*)nullptr);
    hipLaunchKernelGGL((mconv_kernel<1, false, false>), mblk(n24), dim3(256), 0, stream,
                       P1h, P0h, m24, list, nact, WL(7), bs + 7 * C, bb + 7 * C, 24, 24,
                       (float*)nullptr);
    hipLaunchKernelGGL((mconv_kernel<1, false, true>), mblk(n24), dim3(256), 0, stream,
                       P0h, P1h, m24, list, nact, WL(8), bs + 8 * C, bb + 8 * C, 24, 24,
                       out + (long)C * n48);
    // 14. fused 12+6 levels (net3, net4)
    hipLaunchKernelGGL(fused_tail, dim3(1), dim3(512), LDSB, stream,
                       P1h, m12, m6, Wh, bs, bb,
                       out + (long)C * (n48 + n24), out + (long)C * (n48 + n24 + n12));
}

// Round 15
// 287.459 us; speedup vs baseline: 1.3983x; 1.3983x over previous
//
#include <hip/hip_runtime.h>

#define C 16
#define TAPS 27
#define NCONV 17
#define LISTCAP 98304
#define NPAIR 14

typedef _Float16 half8 __attribute__((ext_vector_type(8)));
typedef _Float16 half4 __attribute__((ext_vector_type(4)));
typedef float f32x4 __attribute__((ext_vector_type(4)));

// ---- prep: x NCDHW->NDHWC fp16, zero P1h, per-block counts, weights, m48 ----
// Wh[l][pair][lane][8]: lane co=lane&15, g=lane>>4; k=8g+j; ci=k&15; tap=2p+(k>>4).
__global__ void prep_kernel(const float* __restrict__ x, const int* __restrict__ mask_idx,
                            _Float16* __restrict__ P0h, _Float16* __restrict__ P1h,
                            const float* __restrict__ W, _Float16* __restrict__ Wh,
                            int* __restrict__ counts, float* __restrict__ m48) {
    const int n96 = 96 * 96 * 96;
    int b = blockIdx.x;
    if (b < 3456) {
        int v = b * 256 + threadIdx.x;  // n96 == 3456*256 exactly
        half8 h0, h1;
#pragma unroll
        for (int c = 0; c < 8; c++) h0[c] = (_Float16)x[(long)c * n96 + v];
#pragma unroll
        for (int c = 0; c < 8; c++) h1[c] = (_Float16)x[(long)(c + 8) * n96 + v];
        half8* dp = reinterpret_cast<half8*>(P0h + (long)v * C);
        dp[0] = h0;
        dp[1] = h1;
        half8 zz = {};
        half8* zp = reinterpret_cast<half8*>(P1h + (long)v * C);
        zp[0] = zz;
        zp[1] = zz;
        int act = (mask_idx[v] == 0);
        unsigned long long bl = __ballot(act);
        __shared__ int wsum[4];
        int wid = threadIdx.x >> 6, lane = threadIdx.x & 63;
        if (lane == 0) wsum[wid] = __popcll(bl);
        __syncthreads();
        if (threadIdx.x == 0) counts[b] = wsum[0] + wsum[1] + wsum[2] + wsum[3];
    } else if (b < 3456 + 476) {
        int i = (b - 3456) * 256 + threadIdx.x;
        const int total = NCONV * NPAIR * 64 * 8;
        if (i < total) {
            int j = i & 7;
            int lane = (i >> 3) & 63;
            int p = (i >> 9) % NPAIR;
            int l = (i >> 9) / NPAIR;
            int co = lane & 15;
            int g = lane >> 4;
            int k = 8 * g + j;
            int ci = k & 15;
            int tap = 2 * p + (k >> 4);
            float val = (tap < TAPS) ? W[((l * C + co) * C + ci) * TAPS + tap] : 0.f;
            Wh[i] = (_Float16)val;
        }
    } else {
        // m48: thread per voxel, 3^3 window over mask_idx at [2c-1, 2c+1]
        int i = (b - 3456 - 476) * 256 + threadIdx.x;  // 432*256 == 110592 exactly
        int xx = i % 48, yy = (i / 48) % 48, zc = i / (48 * 48);
        float m = 0.f;
        for (int dz = 0; dz < 3; dz++) {
            int z2 = 2 * zc - 1 + dz;
            if ((unsigned)z2 >= 96u) continue;
            for (int dy = 0; dy < 3; dy++) {
                int y2 = 2 * yy - 1 + dy;
                if ((unsigned)y2 >= 96u) continue;
                for (int dx = 0; dx < 3; dx++) {
                    int x2 = 2 * xx - 1 + dx;
                    if ((unsigned)x2 >= 96u) continue;
                    if (mask_idx[((long)z2 * 96 + y2) * 96 + x2] == 0) m = 1.f;
                }
            }
        }
        m48[i] = m;
    }
}

__global__ void scan_kernel(const int* __restrict__ counts, int* __restrict__ offsets,
                            int* __restrict__ nact, int nb) {
    __shared__ int s[256];
    int t = threadIdx.x;
    const int CH = (nb + 255) / 256;
    int base = t * CH, sum = 0;
    for (int j = 0; j < CH; j++)
        if (base + j < nb) sum += counts[base + j];
    s[t] = sum;
    __syncthreads();
    for (int off = 1; off < 256; off <<= 1) {
        int v = (t >= off) ? s[t - off] : 0;
        __syncthreads();
        s[t] += v;
        __syncthreads();
    }
    int run = s[t] - sum;
    for (int j = 0; j < CH; j++) {
        if (base + j < nb) {
            offsets[base + j] = run;
            run += counts[base + j];
        }
    }
    if (t == 255) *nact = s[255];
}

__global__ void scatter_kernel(const int* __restrict__ mi, const int* __restrict__ offsets,
                               int* __restrict__ list, int n, int cap) {
    int i = blockIdx.x * 256 + threadIdx.x;
    int act = (i < n) && (mi[i] == 0);
    unsigned long long b = __ballot(act);
    __shared__ int wsum[4];
    int wid = threadIdx.x >> 6, lane = threadIdx.x & 63;
    if (lane == 0) wsum[wid] = __popcll(b);
    __syncthreads();
    int wbase = 0;
    for (int w = 0; w < wid; w++) wbase += wsum[w];
    int prefix = __popcll(b & ((1ull << lane) - 1));
    if (act) {
        int pos = offsets[blockIdx.x] + wbase + prefix;
        if (pos < cap) list[pos] = i;
    }
}

// ---- m24 from m48 (hierarchical pool, r13-proven) ----
__global__ void m24_kernel(const float* __restrict__ m48, float* __restrict__ m24) {
    int i = blockIdx.x * 256 + threadIdx.x;
    if (i >= 24 * 24 * 24) return;
    int x = i % 24, y = (i / 24) % 24, z = i / (24 * 24);
    float m = 0.f;
    for (int dz = 0; dz < 3; dz++) {
        int zz = 2 * z - 1 + dz;
        if ((unsigned)zz >= 48u) continue;
        for (int dy = 0; dy < 3; dy++) {
            int yy = 2 * y - 1 + dy;
            if ((unsigned)yy >= 48u) continue;
            for (int dx = 0; dx < 3; dx++) {
                int xx = 2 * x - 1 + dx;
                if ((unsigned)xx >= 48u) continue;
                m = fmaxf(m, m48[((long)zz * 48 + yy) * 48 + xx]);
            }
        }
    }
    m24[i] = m;
}

// ---- MFMA conv (r13-proven) + optional fused fp32 NCDHW output ----
template <int STRIDE, bool SPARSE, bool WF32>
__global__ __launch_bounds__(256) void mconv_kernel(
    const _Float16* __restrict__ in, _Float16* __restrict__ out,
    const float* __restrict__ mask, const int* __restrict__ list,
    const int* __restrict__ nact, const _Float16* __restrict__ Whl,
    const float* __restrict__ bs, const float* __restrict__ bb,
    int Din, int Dout, float* __restrict__ outf) {
    int n = Dout * Dout * Dout;
    int nv;
    if (SPARSE) {
        nv = *nact;
        if (nv > LISTCAP) nv = LISTCAP;
    } else {
        nv = n;
    }
    int tile = blockIdx.x * 4 + (threadIdx.x >> 6);
    if (tile * 16 >= nv) return;  // per-wave exit (no barriers)

    int lane = threadIdx.x & 63;
    int col = lane & 15;
    int g = lane >> 4;
    int s = tile * 16 + col;
    bool val = s < nv;
    int v = 0;
    if (SPARSE) {
        if (val) v = list[s];
    } else {
        v = val ? s : 0;
    }
    int x = v % Dout, y = (v / Dout) % Dout, z = v / (Dout * Dout);

    const half8* wf = reinterpret_cast<const half8*>(Whl);
    half8 a[NPAIR];
#pragma unroll
    for (int p = 0; p < NPAIR; p++) a[p] = wf[p * 64 + lane];

    int half_off = (g & 1) * 8;
    int tg = g >> 1;

    f32x4 acc = {0.f, 0.f, 0.f, 0.f};
#pragma unroll
    for (int p = 0; p < NPAIR; p++) {
        int tap = 2 * p + tg;
        if (tap > TAPS - 1) tap = TAPS - 1;  // dummy half: weights are 0
        int kz = tap / 9, ky = (tap / 3) % 3, kx = tap % 3;
        int zz = STRIDE * z - 1 + kz;
        int yy = STRIDE * y - 1 + ky;
        int xx = STRIDE * x - 1 + kx;
        bool ok = val && ((unsigned)zz < (unsigned)Din) && ((unsigned)yy < (unsigned)Din) &&
                  ((unsigned)xx < (unsigned)Din);
        half8 b = {};
        if (ok) {
            b = *reinterpret_cast<const half8*>(
                in + (long)((zz * Din + yy) * Din + xx) * C + half_off);
        }
        acc = __builtin_amdgcn_mfma_f32_16x16x32_f16(a[p], b, acc, 0, 0, 0);
    }

    if (val) {
        float mk = SPARSE ? 1.f : mask[v];
        int cob = g * 4;
        half4 r;
#pragma unroll
        for (int j = 0; j < 4; j++) {
            float t = fmaxf(acc[j] * bs[cob + j] + bb[cob + j], 0.f) * mk;
            r[j] = (_Float16)t;
            if (WF32) outf[(long)(cob + j) * n + v] = t;
        }
        *reinterpret_cast<half4*>(out + (long)v * C + cob) = r;
    }
}

// ---- fused 12^3 + 6^3 levels: m12/m6 pools + 8 conv layers, one block ----
__global__ __launch_bounds__(512) void fused_tail(
    const _Float16* __restrict__ gin, const float* __restrict__ m24,
    const _Float16* __restrict__ Wh, const float* __restrict__ bs,
    const float* __restrict__ bb, float* __restrict__ out3, float* __restrict__ out4) {
    extern __shared__ _Float16 lds[];
    _Float16* H0 = lds;           // 1728*16 halfs
    _Float16* H1 = lds + 27648;   // 1728*16
    _Float16* G0 = lds + 55296;   // 216*16
    _Float16* G1 = lds + 58752;   // 216*16
    float* Lm12 = (float*)(lds + 62208);  // 1728 f32
    float* Lm6 = Lm12 + 1728;             // 216 f32

    int tid = threadIdx.x;
    int lane = tid & 63;
    int wid = tid >> 6;  // 0..7
    int col = lane & 15, g = lane >> 4;
    int ho = (g & 1) * 8, tg = g >> 1;

    // pools: m12 from m24 (global), m6 from Lm12
    for (int i = tid; i < 1728; i += 512) {
        int x = i % 12, y = (i / 12) % 12, z = i / 144;
        float m = 0.f;
        for (int dz = 0; dz < 3; dz++) {
            int zz = 2 * z - 1 + dz;
            if ((unsigned)zz >= 24u) continue;
            for (int dy = 0; dy < 3; dy++) {
                int yy = 2 * y - 1 + dy;
                if ((unsigned)yy >= 24u) continue;
                for (int dx = 0; dx < 3; dx++) {
                    int xx = 2 * x - 1 + dx;
                    if ((unsigned)xx >= 24u) continue;
                    m = fmaxf(m, m24[((long)zz * 24 + yy) * 24 + xx]);
                }
            }
        }
        Lm12[i] = m;
    }
    __syncthreads();
    for (int i = tid; i < 216; i += 512) {
        int x = i % 6, y = (i / 6) % 6, z = i / 36;
        float m = 0.f;
        for (int dz = 0; dz < 3; dz++) {
            int zz = 2 * z - 1 + dz;
            if ((unsigned)zz >= 12u) continue;
            for (int dy = 0; dy < 3; dy++) {
                int yy = 2 * y - 1 + dy;
                if ((unsigned)yy >= 12u) continue;
                for (int dx = 0; dx < 3; dx++) {
                    int xx = 2 * x - 1 + dx;
                    if ((unsigned)xx >= 12u) continue;
                    m = fmaxf(m, Lm12[(zz * 12 + yy) * 12 + xx]);
                }
            }
        }
        Lm6[i] = m;
    }
    __syncthreads();

    auto layer = [&](const _Float16* ginp, const _Float16* lin, _Float16* lout,
                     int Din, int Dout, int stride, int lidx,
                     const float* mk, float* outf) {
        int n = Dout * Dout * Dout;
        const half8* wf = reinterpret_cast<const half8*>(Wh + (long)lidx * NPAIR * 64 * 8);
        half8 a[NPAIR];
#pragma unroll
        for (int p = 0; p < NPAIR; p++) a[p] = wf[p * 64 + lane];
        const float* bsl = bs + lidx * C;
        const float* bbl = bb + lidx * C;
        int ntiles = (n + 15) / 16;
        for (int t = wid; t < ntiles; t += 8) {
            int s = t * 16 + col;
            bool val = s < n;
            int v = val ? s : 0;
            int x = v % Dout, y = (v / Dout) % Dout, z = v / (Dout * Dout);
            f32x4 acc = {0.f, 0.f, 0.f, 0.f};
#pragma unroll
            for (int p = 0; p < NPAIR; p++) {
                int tap = 2 * p + tg;
                if (tap > TAPS - 1) tap = TAPS - 1;
                int kz = tap / 9, ky = (tap / 3) % 3, kx = tap % 3;
                int zz = stride * z - 1 + kz;
                int yy = stride * y - 1 + ky;
                int xx = stride * x - 1 + kx;
                bool ok = val && ((unsigned)zz < (unsigned)Din) &&
                          ((unsigned)yy < (unsigned)Din) && ((unsigned)xx < (unsigned)Din);
                half8 b = {};
                if (ok) {
                    long off = (long)((zz * Din + yy) * Din + xx) * C + ho;
                    b = ginp ? *reinterpret_cast<const half8*>(ginp + off)
                             : *reinterpret_cast<const half8*>(lin + off);
                }
                acc = __builtin_amdgcn_mfma_f32_16x16x32_f16(a[p], b, acc, 0, 0, 0);
            }
            if (val) {
                float mkv = mk[v];
                int cob = g * 4;
                half4 r;
#pragma unroll
                for (int j = 0; j < 4; j++) {
                    float tt = fmaxf(acc[j] * bsl[cob + j] + bbl[cob + j], 0.f) * mkv;
                    r[j] = (_Float16)tt;
                    if (outf) outf[(long)(cob + j) * n + v] = tt;
                }
                *reinterpret_cast<half4*>(lout + (long)v * C + cob) = r;
            }
        }
        __syncthreads();
    };

    layer(gin, nullptr, H0, 24, 12, 2, 9, Lm12, nullptr);
    layer(nullptr, H0, H1, 12, 12, 1, 10, Lm12, nullptr);
    layer(nullptr, H1, H0, 12, 12, 1, 11, Lm12, nullptr);
    layer(nullptr, H0, H1, 12, 12, 1, 12, Lm12, out3);  // net3
    layer(nullptr, H1, G0, 12, 6, 2, 13, Lm6, nullptr);
    layer(nullptr, G0, G1, 6, 6, 1, 14, Lm6, nullptr);
    layer(nullptr, G1, G0, 6, 6, 1, 15, Lm6, nullptr);
    layer(nullptr, G0, G1, 6, 6, 1, 16, Lm6, out4);     // net4
}

extern "C" void kernel_launch(void* const* d_in, const int* in_sizes, int n_in,
                              void* d_out, int out_size, void* d_ws, size_t ws_size,
                              hipStream_t stream) {
    const float* x = (const float*)d_in[0];
    const int* mask_idx = (const int*)d_in[1];
    const float* W = (const float*)d_in[2];
    const float* bs = (const float*)d_in[3];
    const float* bb = (const float*)d_in[4];
    float* out = (float*)d_out;

    const int n96 = 96 * 96 * 96;
    const int n48 = 48 * 48 * 48;
    const int n24 = 24 * 24 * 24;
    const int n12 = 12 * 12 * 12;
    const int NB = 3456;

    _Float16* P0h = (_Float16*)d_ws;
    _Float16* P1h = P0h + (long)C * n96;
    float* m48 = (float*)(P1h + (long)C * n96);
    float* m24 = m48 + n48;
    _Float16* Wh = (_Float16*)(m24 + n24);  // [17][14][64][8]
    int* list = (int*)(Wh + (long)NCONV * NPAIR * 64 * 8);
    int* counts = list + LISTCAP;
    int* offsets = counts + NB;
    int* nact = offsets + NB;

    const int LDSB = 62208 * 2 + 1728 * 4 + 216 * 4;  // 132192 bytes
    hipFuncSetAttribute(reinterpret_cast<const void*>(&fused_tail),
                        hipFuncAttributeMaxDynamicSharedMemorySize, LDSB);

    // 1. prep (transpose + zero + counts + weights + m48)
    hipLaunchKernelGGL(prep_kernel, dim3(3456 + 476 + 432), dim3(256), 0, stream,
                       x, mask_idx, P0h, P1h, W, Wh, counts, m48);
    // 2-3. compaction
    hipLaunchKernelGGL(scan_kernel, dim3(1), dim3(256), 0, stream, counts, offsets, nact, NB);
    hipLaunchKernelGGL(scatter_kernel, dim3(NB), dim3(256), 0, stream, mask_idx, offsets, list,
                       n96, LISTCAP);
    // 4. m24 from m48
    hipLaunchKernelGGL(m24_kernel, dim3(54), dim3(256), 0, stream, m48, m24);

    auto mblk = [&](long nvox) { return dim3((unsigned)((nvox + 63) / 64)); };
    auto WL = [&](int l) { return Wh + (long)l * NPAIR * 64 * 8; };

    // 5-6. sparse 96 level
    hipLaunchKernelGGL((mconv_kernel<1, true, false>), mblk(LISTCAP), dim3(256), 0, stream,
                       P0h, P1h, (const float*)nullptr, list, nact, WL(0), bs, bb, 96, 96,
                       (float*)nullptr);
    hipLaunchKernelGGL((mconv_kernel<1, true, false>), mblk(LISTCAP), dim3(256), 0, stream,
                       P1h, P0h, (const float*)nullptr, list, nact, WL(1), bs + C, bb + C, 96, 96,
                       (float*)nullptr);
    // 7-9. 48 level; L4 dual-writes net1
    hipLaunchKernelGGL((mconv_kernel<2, false, false>), mblk(n48), dim3(256), 0, stream,
                       P0h, P1h, m48, list, nact, WL(2), bs + 2 * C, bb + 2 * C, 96, 48,
                       (float*)nullptr);
    hipLaunchKernelGGL((mconv_kernel<1, false, false>), mblk(n48), dim3(256), 0, stream,
                       P1h, P0h, m48, list, nact, WL(3), bs + 3 * C, bb + 3 * C, 48, 48,
                       (float*)nullptr);
    hipLaunchKernelGGL((mconv_kernel<1, false, true>), mblk(n48), dim3(256), 0, stream,
                       P0h, P1h, m48, list, nact, WL(4), bs + 4 * C, bb + 4 * C, 48, 48,
                       out);
    // 10-13. 24 level; L8 dual-writes net2
    hipLaunchKernelGGL((mconv_kernel<2, false, false>), mblk(n24), dim3(256), 0, stream,
                       P1h, P0h, m24, list, nact, WL(5), bs + 5 * C, bb + 5 * C, 48, 24,
                       (float*)nullptr);
    hipLaunchKernelGGL((mconv_kernel<1, false, false>), mblk(n24), dim3(256), 0, stream,
                       P0h, P1h, m24, list, nact, WL(6), bs + 6 * C, bb + 6 * C, 24, 24,
                       (float*)nullptr);
    hipLaunchKernelGGL((mconv_kernel<1, false, false>), mblk(n24), dim3(256), 0, stream,
                       P1h, P0h, m24, list, nact, WL(7), bs + 7 * C, bb + 7 * C, 24, 24,
                       (float*)nullptr);
    hipLaunchKernelGGL((mconv_kernel<1, false, true>), mblk(n24), dim3(256), 0, stream,
                       P0h, P1h, m24, list, nact, WL(8), bs + 8 * C, bb + 8 * C, 24, 24,
                       out + (long)C * n48);
    // 14. fused 12+6 levels (pools inside; net3, net4)
    hipLaunchKernelGGL(fused_tail, dim3(1), dim3(512), LDSB, stream,
                       P1h, m24, Wh, bs, bb,
                       out + (long)C * (n48 + n24), out + (long)C * (n48 + n24 + n12));
}

// Round 16
// 207.793 us; speedup vs baseline: 1.9344x; 1.3834x over previous
//
#include <hip/hip_runtime.h>

#define C 16
#define TAPS 27
#define NCONV 17
#define LISTCAP 98304
#define NPAIR 14

typedef _Float16 half8 __attribute__((ext_vector_type(8)));
typedef _Float16 half4 __attribute__((ext_vector_type(4)));
typedef float f32x4 __attribute__((ext_vector_type(4)));

// ---- prep: x NCDHW->NDHWC fp16, zero P1h, per-block counts, weights, m48 ----
// Wh[l][pair][lane][8]: lane co=lane&15, g=lane>>4; k=8g+j; ci=k&15; tap=2p+(k>>4).
__global__ void prep_kernel(const float* __restrict__ x, const int* __restrict__ mask_idx,
                            _Float16* __restrict__ P0h, _Float16* __restrict__ P1h,
                            const float* __restrict__ W, _Float16* __restrict__ Wh,
                            int* __restrict__ counts, float* __restrict__ m48) {
    const int n96 = 96 * 96 * 96;
    int b = blockIdx.x;
    if (b < 3456) {
        int v = b * 256 + threadIdx.x;  // n96 == 3456*256 exactly
        half8 h0, h1;
#pragma unroll
        for (int c = 0; c < 8; c++) h0[c] = (_Float16)x[(long)c * n96 + v];
#pragma unroll
        for (int c = 0; c < 8; c++) h1[c] = (_Float16)x[(long)(c + 8) * n96 + v];
        half8* dp = reinterpret_cast<half8*>(P0h + (long)v * C);
        dp[0] = h0;
        dp[1] = h1;
        half8 zz = {};
        half8* zp = reinterpret_cast<half8*>(P1h + (long)v * C);
        zp[0] = zz;
        zp[1] = zz;
        int act = (mask_idx[v] == 0);
        unsigned long long bl = __ballot(act);
        __shared__ int wsum[4];
        int wid = threadIdx.x >> 6, lane = threadIdx.x & 63;
        if (lane == 0) wsum[wid] = __popcll(bl);
        __syncthreads();
        if (threadIdx.x == 0) counts[b] = wsum[0] + wsum[1] + wsum[2] + wsum[3];
    } else if (b < 3456 + 476) {
        int i = (b - 3456) * 256 + threadIdx.x;
        const int total = NCONV * NPAIR * 64 * 8;
        if (i < total) {
            int j = i & 7;
            int lane = (i >> 3) & 63;
            int p = (i >> 9) % NPAIR;
            int l = (i >> 9) / NPAIR;
            int co = lane & 15;
            int g = lane >> 4;
            int k = 8 * g + j;
            int ci = k & 15;
            int tap = 2 * p + (k >> 4);
            float val = (tap < TAPS) ? W[((l * C + co) * C + ci) * TAPS + tap] : 0.f;
            Wh[i] = (_Float16)val;
        }
    } else {
        // m48: thread per voxel, 3^3 window over mask_idx at [2c-1, 2c+1]
        int i = (b - 3456 - 476) * 256 + threadIdx.x;  // 432*256 == 110592 exactly
        int xx = i % 48, yy = (i / 48) % 48, zc = i / (48 * 48);
        float m = 0.f;
        for (int dz = 0; dz < 3; dz++) {
            int z2 = 2 * zc - 1 + dz;
            if ((unsigned)z2 >= 96u) continue;
            for (int dy = 0; dy < 3; dy++) {
                int y2 = 2 * yy - 1 + dy;
                if ((unsigned)y2 >= 96u) continue;
                for (int dx = 0; dx < 3; dx++) {
                    int x2 = 2 * xx - 1 + dx;
                    if ((unsigned)x2 >= 96u) continue;
                    if (mask_idx[((long)z2 * 96 + y2) * 96 + x2] == 0) m = 1.f;
                }
            }
        }
        m48[i] = m;
    }
}

__global__ void scan_kernel(const int* __restrict__ counts, int* __restrict__ offsets,
                            int* __restrict__ nact, int nb) {
    __shared__ int s[256];
    int t = threadIdx.x;
    const int CH = (nb + 255) / 256;
    int base = t * CH, sum = 0;
    for (int j = 0; j < CH; j++)
        if (base + j < nb) sum += counts[base + j];
    s[t] = sum;
    __syncthreads();
    for (int off = 1; off < 256; off <<= 1) {
        int v = (t >= off) ? s[t - off] : 0;
        __syncthreads();
        s[t] += v;
        __syncthreads();
    }
    int run = s[t] - sum;
    for (int j = 0; j < CH; j++) {
        if (base + j < nb) {
            offsets[base + j] = run;
            run += counts[base + j];
        }
    }
    if (t == 255) *nact = s[255];
}

// ---- scatter + all remaining pools (m24 3^3, m12 7^3, m6 15^3 — all from m48) ----
__global__ void scatter_kernel(const int* __restrict__ mi, const int* __restrict__ offsets,
                               int* __restrict__ list, int cap, const float* __restrict__ m48,
                               float* __restrict__ m24, float* __restrict__ m12,
                               float* __restrict__ m6) {
    int b = blockIdx.x;
    int tid = threadIdx.x;
    if (b < 3456) {
        int i = b * 256 + tid;
        int act = (mi[i] == 0);
        unsigned long long bl = __ballot(act);
        __shared__ int wsum[4];
        int wid = tid >> 6, lane = tid & 63;
        if (lane == 0) wsum[wid] = __popcll(bl);
        __syncthreads();
        int wbase = 0;
        for (int w = 0; w < wid; w++) wbase += wsum[w];
        int prefix = __popcll(bl & ((1ull << lane) - 1));
        if (act) {
            int pos = offsets[b] + wbase + prefix;
            if (pos < cap) list[pos] = i;
        }
    } else if (b < 3456 + 54) {  // m24: thread/voxel, 3^3 over m48
        int i = (b - 3456) * 256 + tid;
        if (i < 24 * 24 * 24) {
            int x = i % 24, y = (i / 24) % 24, z = i / (24 * 24);
            float m = 0.f;
            for (int dz = 0; dz < 3; dz++) {
                int zz = 2 * z - 1 + dz;
                if ((unsigned)zz >= 48u) continue;
                for (int dy = 0; dy < 3; dy++) {
                    int yy = 2 * y - 1 + dy;
                    if ((unsigned)yy >= 48u) continue;
                    for (int dx = 0; dx < 3; dx++) {
                        int xx = 2 * x - 1 + dx;
                        if ((unsigned)xx >= 48u) continue;
                        m = fmaxf(m, m48[((long)zz * 48 + yy) * 48 + xx]);
                    }
                }
            }
            m24[i] = m;
        }
    } else if (b < 3456 + 54 + 432) {  // m12: wave/voxel, 7^3 over m48 at [4c-3,4c+3]
        int wv = (b - 3456 - 54) * 4 + (tid >> 6);
        int lane = tid & 63;
        int x = wv % 12, y = (wv / 12) % 12, z = wv / 144;
        float m = 0.f;
        for (int k = lane; k < 343; k += 64) {
            int dz = k / 49, r = k % 49, dy = r / 7, dx = r % 7;
            int zz = 4 * z - 3 + dz, yy = 4 * y - 3 + dy, xx = 4 * x - 3 + dx;
            if ((unsigned)zz < 48u && (unsigned)yy < 48u && (unsigned)xx < 48u)
                m = fmaxf(m, m48[((long)zz * 48 + yy) * 48 + xx]);
        }
        for (int off = 32; off; off >>= 1) m = fmaxf(m, __shfl_xor(m, off));
        if (lane == 0 && wv < 1728) m12[wv] = m;
    } else {  // m6: wave/voxel, 15^3 over m48 at [8c-7,8c+7]
        int wv = (b - 3456 - 54 - 432) * 4 + (tid >> 6);
        int lane = tid & 63;
        int x = wv % 6, y = (wv / 6) % 6, z = wv / 36;
        float m = 0.f;
        for (int k = lane; k < 3375; k += 64) {
            int dz = k / 225, r = k % 225, dy = r / 15, dx = r % 15;
            int zz = 8 * z - 7 + dz, yy = 8 * y - 7 + dy, xx = 8 * x - 7 + dx;
            if ((unsigned)zz < 48u && (unsigned)yy < 48u && (unsigned)xx < 48u)
                m = fmaxf(m, m48[((long)zz * 48 + yy) * 48 + xx]);
        }
        for (int off = 32; off; off >>= 1) m = fmaxf(m, __shfl_xor(m, off));
        if (lane == 0 && wv < 216) m6[wv] = m;
    }
}

// ---- MFMA conv (r13-proven) + optional fused fp32 NCDHW output ----
template <int STRIDE, bool SPARSE, bool WF32>
__global__ __launch_bounds__(256) void mconv_kernel(
    const _Float16* __restrict__ in, _Float16* __restrict__ out,
    const float* __restrict__ mask, const int* __restrict__ list,
    const int* __restrict__ nact, const _Float16* __restrict__ Whl,
    const float* __restrict__ bs, const float* __restrict__ bb,
    int Din, int Dout, float* __restrict__ outf) {
    int n = Dout * Dout * Dout;
    int nv;
    if (SPARSE) {
        nv = *nact;
        if (nv > LISTCAP) nv = LISTCAP;
    } else {
        nv = n;
    }
    int tile = blockIdx.x * 4 + (threadIdx.x >> 6);
    if (tile * 16 >= nv) return;  // per-wave exit (no barriers)

    int lane = threadIdx.x & 63;
    int col = lane & 15;
    int g = lane >> 4;
    int s = tile * 16 + col;
    bool val = s < nv;
    int v = 0;
    if (SPARSE) {
        if (val) v = list[s];
    } else {
        v = val ? s : 0;
    }
    int x = v % Dout, y = (v / Dout) % Dout, z = v / (Dout * Dout);

    const half8* wf = reinterpret_cast<const half8*>(Whl);
    half8 a[NPAIR];
#pragma unroll
    for (int p = 0; p < NPAIR; p++) a[p] = wf[p * 64 + lane];

    int half_off = (g & 1) * 8;
    int tg = g >> 1;

    f32x4 acc = {0.f, 0.f, 0.f, 0.f};
#pragma unroll
    for (int p = 0; p < NPAIR; p++) {
        int tap = 2 * p + tg;
        if (tap > TAPS - 1) tap = TAPS - 1;  // dummy half: weights are 0
        int kz = tap / 9, ky = (tap / 3) % 3, kx = tap % 3;
        int zz = STRIDE * z - 1 + kz;
        int yy = STRIDE * y - 1 + ky;
        int xx = STRIDE * x - 1 + kx;
        bool ok = val && ((unsigned)zz < (unsigned)Din) && ((unsigned)yy < (unsigned)Din) &&
                  ((unsigned)xx < (unsigned)Din);
        half8 b = {};
        if (ok) {
            b = *reinterpret_cast<const half8*>(
                in + (long)((zz * Din + yy) * Din + xx) * C + half_off);
        }
        acc = __builtin_amdgcn_mfma_f32_16x16x32_f16(a[p], b, acc, 0, 0, 0);
    }

    if (val) {
        float mk = SPARSE ? 1.f : mask[v];
        int cob = g * 4;
        half4 r;
#pragma unroll
        for (int j = 0; j < 4; j++) {
            float t = fmaxf(acc[j] * bs[cob + j] + bb[cob + j], 0.f) * mk;
            r[j] = (_Float16)t;
            if (WF32) outf[(long)(cob + j) * n + v] = t;
        }
        *reinterpret_cast<half4*>(out + (long)v * C + cob) = r;
    }
}

extern "C" void kernel_launch(void* const* d_in, const int* in_sizes, int n_in,
                              void* d_out, int out_size, void* d_ws, size_t ws_size,
                              hipStream_t stream) {
    const float* x = (const float*)d_in[0];
    const int* mask_idx = (const int*)d_in[1];
    const float* W = (const float*)d_in[2];
    const float* bs = (const float*)d_in[3];
    const float* bb = (const float*)d_in[4];
    float* out = (float*)d_out;

    const int n96 = 96 * 96 * 96;
    const int n48 = 48 * 48 * 48;
    const int n24 = 24 * 24 * 24;
    const int n12 = 12 * 12 * 12;
    const int n6 = 6 * 6 * 6;
    const int NB = 3456;

    _Float16* P0h = (_Float16*)d_ws;
    _Float16* P1h = P0h + (long)C * n96;
    float* m48 = (float*)(P1h + (long)C * n96);
    float* m24 = m48 + n48;
    float* m12 = m24 + n24;
    float* m6 = m12 + n12;
    _Float16* Wh = (_Float16*)(m6 + n6);  // [17][14][64][8]
    int* list = (int*)(Wh + (long)NCONV * NPAIR * 64 * 8);
    int* counts = list + LISTCAP;
    int* offsets = counts + NB;
    int* nact = offsets + NB;

    // 1. prep (transpose + zero + counts + weights + m48)
    hipLaunchKernelGGL(prep_kernel, dim3(3456 + 476 + 432), dim3(256), 0, stream,
                       x, mask_idx, P0h, P1h, W, Wh, counts, m48);
    // 2. scan
    hipLaunchKernelGGL(scan_kernel, dim3(1), dim3(256), 0, stream, counts, offsets, nact, NB);
    // 3. scatter + pools (m24, m12, m6 all from m48)
    hipLaunchKernelGGL(scatter_kernel, dim3(3456 + 54 + 432 + 54), dim3(256), 0, stream,
                       mask_idx, offsets, list, LISTCAP, m48, m24, m12, m6);

    auto mblk = [&](long nvox) { return dim3((unsigned)((nvox + 63) / 64)); };
    auto WL = [&](int l) { return Wh + (long)l * NPAIR * 64 * 8; };

    // 4-5. sparse 96 level
    hipLaunchKernelGGL((mconv_kernel<1, true, false>), mblk(LISTCAP), dim3(256), 0, stream,
                       P0h, P1h, (const float*)nullptr, list, nact, WL(0), bs, bb, 96, 96,
                       (float*)nullptr);
    hipLaunchKernelGGL((mconv_kernel<1, true, false>), mblk(LISTCAP), dim3(256), 0, stream,
                       P1h, P0h, (const float*)nullptr, list, nact, WL(1), bs + C, bb + C, 96, 96,
                       (float*)nullptr);
    // 6-8. 48 level; L4 dual-writes net1
    hipLaunchKernelGGL((mconv_kernel<2, false, false>), mblk(n48), dim3(256), 0, stream,
                       P0h, P1h, m48, list, nact, WL(2), bs + 2 * C, bb + 2 * C, 96, 48,
                       (float*)nullptr);
    hipLaunchKernelGGL((mconv_kernel<1, false, false>), mblk(n48), dim3(256), 0, stream,
                       P1h, P0h, m48, list, nact, WL(3), bs + 3 * C, bb + 3 * C, 48, 48,
                       (float*)nullptr);
    hipLaunchKernelGGL((mconv_kernel<1, false, true>), mblk(n48), dim3(256), 0, stream,
                       P0h, P1h, m48, list, nact, WL(4), bs + 4 * C, bb + 4 * C, 48, 48,
                       out);
    // 9-12. 24 level; L8 dual-writes net2
    hipLaunchKernelGGL((mconv_kernel<2, false, false>), mblk(n24), dim3(256), 0, stream,
                       P1h, P0h, m24, list, nact, WL(5), bs + 5 * C, bb + 5 * C, 48, 24,
                       (float*)nullptr);
    hipLaunchKernelGGL((mconv_kernel<1, false, false>), mblk(n24), dim3(256), 0, stream,
                       P0h, P1h, m24, list, nact, WL(6), bs + 6 * C, bb + 6 * C, 24, 24,
                       (float*)nullptr);
    hipLaunchKernelGGL((mconv_kernel<1, false, false>), mblk(n24), dim3(256), 0, stream,
                       P1h, P0h, m24, list, nact, WL(7), bs + 7 * C, bb + 7 * C, 24, 24,
                       (float*)nullptr);
    hipLaunchKernelGGL((mconv_kernel<1, false, true>), mblk(n24), dim3(256), 0, stream,
                       P0h, P1h, m24, list, nact, WL(8), bs + 8 * C, bb + 8 * C, 24, 24,
                       out + (long)C * n48);
    // 13-16. 12 level; L12 dual-writes net3
    hipLaunchKernelGGL((mconv_kernel<2, false, false>), mblk(n12), dim3(256), 0, stream,
                       P1h, P0h, m12, list, nact, WL(9), bs + 9 * C, bb + 9 * C, 24, 12,
                       (float*)nullptr);
    hipLaunchKernelGGL((mconv_kernel<1, false, false>), mblk(n12), dim3(256), 0, stream,
                       P0h, P1h, m12, list, nact, WL(10), bs + 10 * C, bb + 10 * C, 12, 12,
                       (float*)nullptr);
    hipLaunchKernelGGL((mconv_kernel<1, false, false>), mblk(n12), dim3(256), 0, stream,
                       P1h, P0h, m12, list, nact, WL(11), bs + 11 * C, bb + 11 * C, 12, 12,
                       (float*)nullptr);
    hipLaunchKernelGGL((mconv_kernel<1, false, true>), mblk(n12), dim3(256), 0, stream,
                       P0h, P1h, m12, list, nact, WL(12), bs + 12 * C, bb + 12 * C, 12, 12,
                       out + (long)C * (n48 + n24));
    // 17-20. 6 level; L16 dual-writes net4
    hipLaunchKernelGGL((mconv_kernel<2, false, false>), mblk(n6), dim3(256), 0, stream,
                       P1h, P0h, m6, list, nact, WL(13), bs + 13 * C, bb + 13 * C, 12, 6,
                       (float*)nullptr);
    hipLaunchKernelGGL((mconv_kernel<1, false, false>), mblk(n6), dim3(256), 0, stream,
                       P0h, P1h, m6, list, nact, WL(14), bs + 14 * C, bb + 14 * C, 6, 6,
                       (float*)nullptr);
    hipLaunchKernelGGL((mconv_kernel<1, false, false>), mblk(n6), dim3(256), 0, stream,
                       P1h, P0h, m6, list, nact, WL(15), bs + 15 * C, bb + 15 * C, 6, 6,
                       (float*)nullptr);
    hipLaunchKernelGGL((mconv_kernel<1, false, true>), mblk(n6), dim3(256), 0, stream,
                       P0h, P1h, m6, list, nact, WL(16), bs + 16 * C, bb + 16 * C, 6, 6,
                       out + (long)C * (n48 + n24 + n12));
}